// Round 7
// baseline (1122.409 us; speedup 1.0000x reference)
//
#include <hip/hip_runtime.h>
#include <hip/hip_bf16.h>
#include <math.h>

#define T_TOK 1024
#define H_DIM 1024
#define E_NUM 64
#define I_DIM 768
#define TOPK  8
#define TOTROWS (T_TOK*TOPK)

typedef __attribute__((ext_vector_type(8))) short short8;
typedef __attribute__((ext_vector_type(4))) float f32x4;

__device__ __forceinline__ unsigned short f2bf(float f){
  __hip_bfloat16 h = __float2bfloat16(f);
  return *reinterpret_cast<unsigned short*>(&h);
}
__device__ __forceinline__ float bf2f(unsigned int bits16){
  unsigned int u = bits16 << 16;
  float f; __builtin_memcpy(&f, &u, 4); return f;
}
// XOR-swizzle granule permutation: k-granule g of row r lives at LDS granule
// g ^ swzf(r). Involution; spreads 128B-stride rows across 8 bank-groups.
__device__ __forceinline__ int swzf(int r){ return (r ^ (r >> 3)) & 7; }

// ---------------- router: fp32 logits + top-8 (softmax cancels in renorm) ----------------
__global__ __launch_bounds__(256)
void router_kernel(const float* __restrict__ x, const float* __restrict__ gw,
                   int* __restrict__ counts, int* __restrict__ tk_idx,
                   float* __restrict__ tk_w)
{
  __shared__ float xs[H_DIM];
  __shared__ float lg[E_NUM];
  const int t = blockIdx.x, tid = threadIdx.x;
  reinterpret_cast<float4*>(xs)[tid] =
      reinterpret_cast<const float4*>(x + (size_t)t*H_DIM)[tid];
  __syncthreads();
  const int wid = tid >> 6, lane = tid & 63;
  for (int e = wid; e < E_NUM; e += 4){
    const float* wrow = gw + (size_t)e*H_DIM;
    float p = 0.f;
    #pragma unroll
    for (int h = 0; h < H_DIM/64; ++h) p += xs[h*64 + lane] * wrow[h*64 + lane];
    #pragma unroll
    for (int off = 32; off; off >>= 1) p += __shfl_xor(p, off);
    if (lane == 0) lg[e] = p;
  }
  __syncthreads();
  if (wid == 0){
    float v = lg[lane];
    float m = v;
    #pragma unroll
    for (int off = 32; off; off >>= 1) m = fmaxf(m, __shfl_xor(m, off));
    float p = expf(v - m);       // unnormalized prob; normalization cancels in renorm
    float pc = p, wsum = 0.f, myv = 0.f; int myi = -1;
    for (int k = 0; k < TOPK; ++k){
      float bv = pc; int bi = lane;
      #pragma unroll
      for (int off = 32; off; off >>= 1){
        float ov = __shfl_xor(bv, off); int oi = __shfl_xor(bi, off);
        if (ov > bv || (ov == bv && oi < bi)) { bv = ov; bi = oi; }
      }
      wsum += bv;
      if (lane == bi) pc = -1.f;
      if (lane == k) { myv = bv; myi = bi; }
    }
    if (lane < TOPK){
      tk_idx[t*TOPK + lane] = myi;
      tk_w  [t*TOPK + lane] = myv / wsum;
      atomicAdd(&counts[myi], 1);
    }
  }
}

__global__ void prefix_kernel(const int* __restrict__ counts, int* __restrict__ offsets){
  if (threadIdx.x == 0){
    int s = 0;
    for (int e = 0; e < E_NUM; ++e){ offsets[e] = s; s += counts[e]; }
  }
}

__global__ __launch_bounds__(256)
void scatter_kernel(const int* __restrict__ tk_idx, const float* __restrict__ tk_w,
                    const int* __restrict__ offsets, int* __restrict__ cursor,
                    int* __restrict__ rowmap, float* __restrict__ roww,
                    int* __restrict__ tokrow)
{
  int a = blockIdx.x*256 + threadIdx.x;
  if (a >= TOTROWS) return;
  int e = tk_idx[a];
  int pos = atomicAdd(&cursor[e], 1);
  int row = offsets[e] + pos;
  rowmap[row] = a >> 3;          // token index
  roww[row]   = tk_w[a];
  tokrow[a]   = row;             // inverse map: (token,slot) -> sorted row
}

__global__ __launch_bounds__(256)
void xcvt_kernel(const float* __restrict__ x, unsigned short* __restrict__ xb){
  int i = blockIdx.x*256 + threadIdx.x;       // 262144 float4 groups
  float4 v = reinterpret_cast<const float4*>(x)[i];
  uint2 o;
  o.x = (unsigned int)f2bf(v.x) | ((unsigned int)f2bf(v.y) << 16);
  o.y = (unsigned int)f2bf(v.z) | ((unsigned int)f2bf(v.w) << 16);
  reinterpret_cast<uint2*>(xb)[i] = o;
}

// act = silu(g) * u * roww[row], in place into g (bf16)
__global__ __launch_bounds__(256)
void act_kernel(uint4* __restrict__ g, const uint4* __restrict__ u,
                const float* __restrict__ roww)
{
  int i = blockIdx.x*256 + threadIdx.x;       // per 8 bf16; total 786432
  float w = roww[i / (I_DIM/8)];
  uint4 gv = g[i], uv = u[i], ov;
  unsigned int* gp = reinterpret_cast<unsigned int*>(&gv);
  unsigned int* up = reinterpret_cast<unsigned int*>(&uv);
  unsigned int* op = reinterpret_cast<unsigned int*>(&ov);
  #pragma unroll
  for (int j = 0; j < 4; ++j){
    float g0 = bf2f(gp[j] & 0xffffu), g1 = bf2f(gp[j] >> 16);
    float u0 = bf2f(up[j] & 0xffffu), u1 = bf2f(up[j] >> 16);
    float s0 = g0 / (1.f + expf(-g0)) * u0 * w;
    float s1 = g1 / (1.f + expf(-g1)) * u1 * w;
    op[j] = (unsigned int)f2bf(s0) | ((unsigned int)f2bf(s1) << 16);
  }
  g[i] = ov;
}

// out[t][h] = sum over the token's 8 expert rows of dbuf (bf16 -> fp32)
__global__ __launch_bounds__(256)
void combine_kernel(const unsigned short* __restrict__ dbuf,
                    const int* __restrict__ tokrow, float* __restrict__ out)
{
  const int t = blockIdx.x, h4 = threadIdx.x;   // 256 threads x 4 H each
  float a0=0.f, a1=0.f, a2=0.f, a3=0.f;
  #pragma unroll
  for (int r = 0; r < TOPK; ++r){
    int row = tokrow[t*TOPK + r];
    uint2 v = *reinterpret_cast<const uint2*>(dbuf + (size_t)row*H_DIM + h4*4);
    a0 += bf2f(v.x & 0xffffu); a1 += bf2f(v.x >> 16);
    a2 += bf2f(v.y & 0xffffu); a3 += bf2f(v.y >> 16);
  }
  float4 o = {a0, a1, a2, a3};
  reinterpret_cast<float4*>(out + (size_t)t*H_DIM)[h4] = o;
}

// --------------- grouped expert GEMM, 256x128 tile, BK=64, bf16 MFMA ---------------
// 512 threads = 8 waves in a 4x2 grid; per-wave output 64x64 (4x4 16x16 frags).
// A: bf16 rows (gathered via rowmap if GATHER_A, else expert-sorted linear),
//    staged via global_load_lds(16B), LDS linear dest + source-pre-swizzled granules.
//    A-loads stay CACHED (xb/gbuf are hot and must survive the weight stream).
// B: fp32 K-major per expert [K][N], loaded NON-TEMPORAL (zero reuse; nt keeps the
//    576MB/launch weight stream from evicting xb/gbuf out of L2/L3), transposed +
//    converted to bf16 during reg-staging into the same granule-swizzled [n][k] layout.
// C: bf16 store to Cbuf[row][N].  blockIdx.z selects (B0,C0) vs (B1,C1).
// Waves whose 64-row block is entirely padding (wr*64 >= mrows) skip fragment
// reads + MFMA (barriers/staging stay uniform) — halves matrix work at cnt<=128.
template<int K, int N, bool GATHER_A>
__global__ __launch_bounds__(512)
void gemm_moe(const unsigned short* __restrict__ Asrc, int lda,
              const float* __restrict__ B0, const float* __restrict__ B1,
              unsigned short* __restrict__ C0, unsigned short* __restrict__ C1,
              const int* __restrict__ counts, const int* __restrict__ offsets,
              const int* __restrict__ rowmap)
{
  constexpr int BM = 256, BN = 128, BK = 64;
  const float* Bsrc = blockIdx.z ? B1 : B0;
  unsigned short* Cbuf = blockIdx.z ? C1 : C0;
  const int e  = blockIdx.x >> 2;
  const int mt = blockIdx.x & 3;
  const int cnt = counts[e];
  const int m0 = mt * BM;
  if (m0 >= cnt) return;
  const int rows0 = offsets[e];
  const int mrows = min(BM, cnt - m0);
  const int n0 = blockIdx.y * BN;

  __shared__ __align__(16) unsigned short As[BM*BK];  // [row][k], granule-swizzled (32KB)
  __shared__ __align__(16) unsigned short Bs[BN*BK];  // [n][k],  granule-swizzled (16KB)
  __shared__ int rm_s[BM];

  const int tid = threadIdx.x;
  if (tid < BM) rm_s[tid] = (tid < mrows) ? rowmap[rows0 + m0 + tid]
                                          : rowmap[rows0 + m0];
  __syncthreads();

  // A staging: 4 x global_load_lds(16B) per thread per K-tile. LDS dest is
  // lane-linear (slot*16B); the k-granule is pre-swizzled on the SOURCE side.
  const unsigned short* a_src[4];
  #pragma unroll
  for (int i = 0; i < 4; ++i){
    int slot = i*512 + tid;           // 0..2047
    int row  = slot >> 3;             // 0..255
    int cg   = (slot & 7) ^ swzf(row);
    long grow;
    if (GATHER_A) grow = rm_s[row];
    else { grow = rows0 + m0 + row; if (grow > TOTROWS-1) grow = TOTROWS-1; }
    a_src[i] = Asrc + grow*(long)lda + cg*8;
  }

  // B staging map: per half-wave, lanes cover 128 contiguous floats (coalesced).
  const int nn4 = (tid & 31) * 4;     // n offset 0..124
  const int kk  = 2 * (tid >> 5);     // even 0..30
  const float* b_exp = Bsrc + (size_t)e*K*N + n0 + nn4;

  const int wid = tid >> 6, lane = tid & 63;
  const int wr = wid >> 1, wc = wid & 1;          // 4x2 wave grid
  const int lrow = lane & 15, kq = lane >> 4;
  const bool wactive = (wr*64) < mrows;           // wave's rows not all padding
  int arow[4], afx[4], bn[4], bfx[4];
  #pragma unroll
  for (int mf = 0; mf < 4; ++mf){ arow[mf] = wr*64 + mf*16 + lrow; afx[mf] = swzf(arow[mf]); }
  #pragma unroll
  for (int nf = 0; nf < 4; ++nf){ bn[nf]   = wc*64 + nf*16 + lrow; bfx[nf] = swzf(bn[nf]); }

  f32x4 acc[4][4];
  #pragma unroll
  for (int ai = 0; ai < 4; ++ai)
    #pragma unroll
    for (int bj = 0; bj < 4; ++bj) acc[ai][bj] = (f32x4){0.f,0.f,0.f,0.f};

  for (int kt = 0; kt < K/BK; ++kt){
    const int k0 = kt * BK;
    __syncthreads();
    #pragma unroll
    for (int i = 0; i < 4; ++i){
      int slot = i*512 + tid;
      __builtin_amdgcn_global_load_lds(
        (const __attribute__((address_space(1))) unsigned int*)(const void*)(a_src[i] + k0),
        (__attribute__((address_space(3))) unsigned int*)(void*)(&As[slot*8]),
        16, 0, 0);
    }
    #pragma unroll
    for (int r = 0; r < 2; ++r){
      int k = kk + 32*r;                       // even k in [0,64)
      const float* src = b_exp + (size_t)(k0 + k)*N;
      f32x4 v0 = __builtin_nontemporal_load(reinterpret_cast<const f32x4*>(src));
      f32x4 v1 = __builtin_nontemporal_load(reinterpret_cast<const f32x4*>(src + N));
      int kb = k*2;                            // byte offset within row (pre-swizzle)
      #pragma unroll
      for (int j = 0; j < 4; ++j){
        int n = nn4 + j;
        unsigned int pk = (unsigned int)f2bf(v0[j]) | ((unsigned int)f2bf(v1[j]) << 16);
        int byte = n*128 + (kb & 15) + ((((kb>>4) ^ swzf(n)) & 7) << 4);
        *reinterpret_cast<unsigned int*>(reinterpret_cast<char*>(Bs) + byte) = pk;
      }
    }
    __syncthreads();
    if (wactive){
      #pragma unroll
      for (int ks = 0; ks < 2; ++ks){
        short8 av[4], bv[4];
        #pragma unroll
        for (int mf = 0; mf < 4; ++mf){
          int g = ((ks*4 + kq) ^ afx[mf]) & 7;
          av[mf] = *reinterpret_cast<const short8*>(
                     reinterpret_cast<const char*>(As) + arow[mf]*128 + (g << 4));
        }
        #pragma unroll
        for (int nf = 0; nf < 4; ++nf){
          int g = ((ks*4 + kq) ^ bfx[nf]) & 7;
          bv[nf] = *reinterpret_cast<const short8*>(
                     reinterpret_cast<const char*>(Bs) + bn[nf]*128 + (g << 4));
        }
        #pragma unroll
        for (int mf = 0; mf < 4; ++mf)
          #pragma unroll
          for (int nf = 0; nf < 4; ++nf)
            acc[mf][nf] = __builtin_amdgcn_mfma_f32_16x16x32_bf16(av[mf], bv[nf], acc[mf][nf], 0, 0, 0);
      }
    }
  }

  if (wactive){
    #pragma unroll
    for (int mf = 0; mf < 4; ++mf){
      #pragma unroll
      for (int r = 0; r < 4; ++r){
        int rt = wr*64 + mf*16 + kq*4 + r;     // C/D: col=lane&15, row=(lane>>4)*4+reg
        if (rt < mrows){
          #pragma unroll
          for (int nf = 0; nf < 4; ++nf){
            int col = n0 + wc*64 + nf*16 + lrow;
            Cbuf[(size_t)(rows0 + m0 + rt)*N + col] = f2bf(acc[mf][nf][r]);
          }
        }
      }
    }
  }
}

extern "C" void kernel_launch(void* const* d_in, const int* in_sizes, int n_in,
                              void* d_out, int out_size, void* d_ws, size_t ws_size,
                              hipStream_t stream)
{
  const float* x      = (const float*)d_in[0];   // [1,1024,1024]
  const float* gate_w = (const float*)d_in[1];   // [64,1024]
  const float* w_gate = (const float*)d_in[2];   // [64,1024,768]
  const float* w_up   = (const float*)d_in[3];   // [64,1024,768]
  const float* w_down = (const float*)d_in[4];   // [64,768,1024]
  float* out = (float*)d_out;

  char* ws = (char*)d_ws;
  int*   counts  = (int*)(ws);                    // 256B
  int*   cursor  = (int*)(ws + 256);              // 256B
  int*   offsets = (int*)(ws + 512);              // 256B
  int*   tk_idx  = (int*)(ws + 1024);             // 32KB
  float* tk_w    = (float*)(ws + 33792);          // 32KB
  int*   rowmap  = (int*)(ws + 66560);            // 32KB
  float* roww    = (float*)(ws + 99328);          // 32KB
  int*   tokrow  = (int*)(ws + 132096);           // 32KB
  unsigned short* xb   = (unsigned short*)(ws + 164864);            // 2MB
  unsigned short* gbuf = (unsigned short*)(ws + 164864 + 2097152);  // 12MB
  unsigned short* ubuf = gbuf + (size_t)TOTROWS * I_DIM;            // 12MB
  unsigned short* dbuf = ubuf;                    // 16MB, aliases dead ubuf
  // total ws usage ~= 164864 + 2MB + 12MB + 16MB ~= 30.2MB

  (void)hipMemsetAsync(ws, 0, 512, stream);       // counts + cursor

  router_kernel<<<T_TOK, 256, 0, stream>>>(x, gate_w, counts, tk_idx, tk_w);
  prefix_kernel<<<1, 64, 0, stream>>>(counts, offsets);
  scatter_kernel<<<TOTROWS/256, 256, 0, stream>>>(tk_idx, tk_w, offsets, cursor,
                                                  rowmap, roww, tokrow);
  xcvt_kernel<<<(T_TOK*H_DIM/4)/256, 256, 0, stream>>>(x, xb);

  // gate (z=0) + up (z=1) in one launch
  gemm_moe<H_DIM, I_DIM, true><<<dim3(E_NUM*4, I_DIM/128, 2), 512, 0, stream>>>(
      xb, H_DIM, w_gate, w_up, gbuf, ubuf, counts, offsets, rowmap);

  act_kernel<<<(TOTROWS*I_DIM/8)/256, 256, 0, stream>>>(
      (uint4*)gbuf, (const uint4*)ubuf, roww);

  gemm_moe<I_DIM, H_DIM, false><<<dim3(E_NUM*4, H_DIM/128, 1), 512, 0, stream>>>(
      gbuf, I_DIM, w_down, w_down, dbuf, dbuf, counts, offsets, rowmap);

  combine_kernel<<<T_TOK, 256, 0, stream>>>(dbuf, tokrow, out);
}